// Round 9
// baseline (901.943 us; speedup 1.0000x reference)
//
#include <hip/hip_runtime.h>
#include <hip/hip_bf16.h>
#include <hip/hip_cooperative_groups.h>

namespace cg = cooperative_groups;

#define NND 6890
#define NED 41340

typedef __bf16 bf16x8 __attribute__((ext_vector_type(8)));
typedef float f32x4 __attribute__((ext_vector_type(4)));
typedef unsigned short u16x4 __attribute__((ext_vector_type(4)));

__device__ inline unsigned short f32_bf16(float f) {
  unsigned int u = __float_as_uint(f);
  unsigned int r = (u + 0x7FFFu + ((u >> 16) & 1u)) >> 16;
  return (unsigned short)r;
}
__device__ inline void split2(float v, unsigned short& hi, unsigned short& lo) {
  unsigned short h = f32_bf16(v);
  float hf = __uint_as_float((unsigned int)h << 16);
  hi = h;
  lo = f32_bf16(v - hf);
}
__device__ inline float elu_f(float v) { return v > 0.f ? v : (expf(v) - 1.f); }

__device__ __forceinline__ void gload_lds16(const void* g, void* l) {
  __builtin_amdgcn_global_load_lds((const __attribute__((address_space(1))) void*)g,
                                   (__attribute__((address_space(3))) void*)l, 16, 0, 0);
}

struct MP {
  const float *x, *pseudo, *W_lin, *b_lin, *w1, *r1, *bi1, *w2, *r2, *bi2;
  const float *w3, *r3, *bi3, *W1, *b1, *W2, *b2;
  const int* ei;
  unsigned short *Bh, *Bl, *h3h, *h3l, *xh, *xl, *Wth, *Wtl, *h4b, *W2t;
  float *h0, *h1, *h2, *Pbuf, *stats, *ew, *deginv, *lse, *outp;
  int *ek, *deg, *rowptr, *cursor, *csr;
};

// ---- phase: one prep tile (weight splits / x split / W2^T cast) ----
__device__ void prep_tile(char* smem, const MP& p, int b, int tid) {
  if (b < 323) {
    const int tstart[9] = {0, 17, 30, 31, 81, 83, 283, 291, 323};
    const int jK[8]    = {544, 400, 16, 800, 32, 1600, 64, 128};
    const int jF[8]    = {16, 32, 32, 64, 64, 128, 128, 256};
    const int jldt[8]  = {544, 416, 416, 832, 832, 1664, 1664, 128};
    const int jkoff[8] = {0, 0, 400, 0, 800, 0, 1600, 0};
    const int jdst[8]  = {0, 8704, 8704, 22016, 22016, 75264, 75264, 288256};
    int job = 0;
    while (job < 7 && b >= tstart[job + 1]) ++job;
    int t = b - tstart[job];
    int fxc = (jF[job] + 31) >> 5;
    int kt = t / fxc, ft = t % fxc;
    const float* src;
    switch (job) {
      case 0: src = p.W_lin; break;
      case 1: src = p.w1; break;
      case 2: src = p.r1; break;
      case 3: src = p.w2; break;
      case 4: src = p.r2; break;
      case 5: src = p.w3; break;
      case 6: src = p.r3; break;
      default: src = p.W1; break;
    }
    int K = jK[job], F = jF[job], ldt = jldt[job], koff = jkoff[job];
    unsigned short* th = p.Wth + jdst[job];
    unsigned short* tl = p.Wtl + jdst[job];
    int k0 = kt * 32, c0 = ft * 32;
    float (*tbuf)[33] = (float(*)[33])smem;
    int tx = tid & 31, ty = tid >> 5;
    for (int j = ty; j < 32; j += 8) {
      int gk = k0 + j, gc = c0 + tx;
      tbuf[j][tx] = (gk < K && gc < F) ? src[(size_t)gk * F + gc] : 0.f;
    }
    __syncthreads();
    for (int j = ty; j < 32; j += 8) {
      int gc = c0 + j, gk = k0 + tx;
      if (gc < F && gk < K) {
        unsigned short h, lo2;
        split2(tbuf[tx][j], h, lo2);
        th[(size_t)gc * ldt + koff + gk] = h;
        tl[(size_t)gc * ldt + koff + gk] = lo2;
      }
    }
  } else if (b < 3984) {
    int i = (b - 323) * 256 + tid;
    if (i < NND * 136) {
      f32x4 v = *(const f32x4*)(p.x + 4 * (size_t)i);
      u16x4 h, l;
#pragma unroll
      for (int j = 0; j < 4; ++j) {
        unsigned short hh, ll;
        split2(v[j], hh, ll);
        h[j] = hh; l[j] = ll;
      }
      *(u16x4*)(p.xh + 4 * (size_t)i) = h;
      *(u16x4*)(p.xl + 4 * (size_t)i) = l;
    }
  } else {
    int t = b - 3984;
    int c0 = (t % 216) * 32, k0 = (t / 216) * 32;
    float (*tbuf)[33] = (float(*)[33])smem;
    int tx = tid & 31, ty = tid >> 5;
    for (int j = ty; j < 32; j += 8) {
      int gk = k0 + j, gc = c0 + tx;
      tbuf[j][tx] = (gk < 256 && gc < NND) ? p.W2[(size_t)gk * NND + gc] : 0.f;
    }
    __syncthreads();
    for (int j = ty; j < 32; j += 8) {
      int gc = c0 + j, gk = k0 + tx;
      if (gc < NND && gk < 256) p.W2t[(size_t)gc * 256 + gk] = f32_bf16(tbuf[tx][j]);
    }
  }
}

// ---- phase: mid GEMM (bf16x3). OM: 0=f32 fused, 2=bf16 fused, 3=partial->P ----
template <int BN, int OM>
__device__ void mid_gemm(char* smem, const unsigned short* Ah, const unsigned short* Al,
                         const unsigned short* Wh, const unsigned short* Wl,
                         const float* bias, float* outF, unsigned short* outB, float* P,
                         int Kd, int F, int KS, int bid, int nbk, int tid) {
  constexpr int AE = 64 * 32;
  constexpr int WE = BN * 32;
  constexpr int NF = BN / 16;
  constexpr int BUFSZ = 2 * AE + 2 * WE;
  unsigned short* ldsbase = (unsigned short*)smem;
  int wave = tid >> 6, lane = tid & 63;
  int g = lane >> 4, r = lane & 15;
  const int gy = (NND + 63) >> 6;  // 108
  const int gx = F / BN;
  int nt = Kd >> 5;
  int ntiles = gx * gy * KS;
  int rA = wave * 16 + r;
  int aoff = rA * 32 + ((g + rA) & 3) * 8;

  for (int t = bid; t < ntiles; t += nbk) {
    int z = t / (gx * gy);
    int rem = t - z * (gx * gy);
    int by = rem / gx, bx = rem - by * gx;
    int row0 = by * 64, col0 = bx * BN;
    int ta = z * nt / KS, tb = (z + 1) * nt / KS;
    int n = tb - ta;

    auto STAGE = [&](int buf, int kb) {
      unsigned short* lds = ldsbase + buf * BUFSZ;
      {
        int rr = tid >> 2, pos = tid & 3;
        int c = (pos - rr) & 3;
        int gra = row0 + rr; if (gra >= NND) gra = NND - 1;
        size_t so = (size_t)gra * Kd + kb + c * 8;
        gload_lds16(Ah + so, lds + wave * 512);
        gload_lds16(Al + so, lds + AE + wave * 512);
      }
#pragma unroll
      for (int it = 0; it < (4 * BN + 255) / 256; ++it) {
        int idx = it * 256 + tid;
        if (idx < 4 * BN) {
          int rr = idx >> 2, pos = idx & 3;
          int c = (pos - rr) & 3;
          size_t so = (size_t)(col0 + rr) * Kd + kb + c * 8;
          gload_lds16(Wh + so, lds + 2 * AE + (it * 256 + wave * 64) * 8);
          gload_lds16(Wl + so, lds + 2 * AE + WE + (it * 256 + wave * 64) * 8);
        }
      }
    };

    f32x4 acc[NF];
#pragma unroll
    for (int nn = 0; nn < NF; ++nn)
#pragma unroll
      for (int q = 0; q < 4; ++q) acc[nn][q] = 0.f;

    STAGE(0, ta * 32);
    __syncthreads();
    for (int tt = 0; tt < n; ++tt) {
      int buf = tt & 1;
      if (tt + 1 < n) STAGE(buf ^ 1, (ta + tt + 1) * 32);
      unsigned short* lds = ldsbase + buf * BUFSZ;
      bf16x8 fah = *(const bf16x8*)(lds + aoff);
      bf16x8 fal = *(const bf16x8*)(lds + AE + aoff);
#pragma unroll
      for (int nn = 0; nn < NF; ++nn) {
        int rW = nn * 16 + r;
        int woff = rW * 32 + ((g + rW) & 3) * 8;
        bf16x8 fbh = *(const bf16x8*)(lds + 2 * AE + woff);
        bf16x8 fbl = *(const bf16x8*)(lds + 2 * AE + WE + woff);
        acc[nn] = __builtin_amdgcn_mfma_f32_16x16x32_bf16(fah, fbh, acc[nn], 0, 0, 0);
        acc[nn] = __builtin_amdgcn_mfma_f32_16x16x32_bf16(fal, fbh, acc[nn], 0, 0, 0);
        acc[nn] = __builtin_amdgcn_mfma_f32_16x16x32_bf16(fah, fbl, acc[nn], 0, 0, 0);
      }
      __syncthreads();
    }
#pragma unroll
    for (int nn = 0; nn < NF; ++nn) {
      int gc = col0 + nn * 16 + r;
      float bv = (OM == 3) ? 0.f : bias[gc];
#pragma unroll
      for (int q = 0; q < 4; ++q) {
        int gr = row0 + wave * 16 + g * 4 + q;
        if (gr < NND) {
          if (OM == 3) {
            P[((size_t)z * NND + gr) * F + gc] = acc[nn][q];
          } else {
            float v = elu_f(acc[nn][q] + bv);
            if (OM == 0) outF[(size_t)gr * F + gc] = v;
            else outB[(size_t)gr * F + gc] = f32_bf16(v);
          }
        }
      }
    }
  }
}

// ---- phase: combine split-K partials + bias + elu ----
__device__ void combine_phase(const float* P, const float* bias, float* outF,
                              unsigned short* outH, unsigned short* outL,
                              int F, int KS, int gidx, int gstride) {
  int fv = F >> 2;
  int total = NND * fv;
  for (int i4 = gidx; i4 < total; i4 += gstride) {
    int gr = i4 / fv, c4 = (i4 - gr * fv) * 4;
    f32x4 s = {0.f, 0.f, 0.f, 0.f};
    for (int z = 0; z < KS; ++z)
      s += *(const f32x4*)(P + ((size_t)z * NND + gr) * F + c4);
    f32x4 bv = *(const f32x4*)(bias + c4);
#pragma unroll
    for (int j = 0; j < 4; ++j) s[j] = elu_f(s[j] + bv[j]);
    if (outH) {
      u16x4 h, l;
#pragma unroll
      for (int j = 0; j < 4; ++j) {
        unsigned short hh, ll;
        split2(s[j], hh, ll);
        h[j] = hh; l[j] = ll;
      }
      *(u16x4*)(outH + (size_t)gr * F + c4) = h;
      *(u16x4*)(outL + (size_t)gr * F + c4) = l;
    } else {
      *(f32x4*)(outF + (size_t)gr * F + c4) = s;
    }
  }
}

// ---- phase: B-row build (atomic-free, 4 edge-phase planes) ----
__device__ void b_build_phase(char* smem, const float* x, const int* ecol,
                              const float* ew4, const int* ek4, const int* rowptr,
                              const int* csr, const float* deginv,
                              unsigned short* Bh, unsigned short* Bl,
                              int Fin, int bid, int nbk, int tid) {
  float* lds = (float*)smem;
  int nb4 = 25 * Fin;
  int tpr = 4 * Fin;
  int rpb = 256 / tpr;
  int group = tid / tpr;
  int t2 = tid - group * tpr;
  int j = t2 / Fin, i = t2 - j * Fin;
  float* plane = lds + (group * 4 + j) * nb4;
  int nrt = (NND + rpb - 1) / rpb;
  for (int rt = bid; rt < nrt; rt += nbk) {
    int r = rt * rpb + group;
    for (int tt = tid; tt < 4 * nb4 * rpb; tt += 256) lds[tt] = 0.f;
    __syncthreads();
    if (r < NND) {
      int p0 = rowptr[r], p1 = rowptr[r + 1];
      for (int p = p0 + j; p < p1; p += 4) {
        int e = csr[p];
        int c = ecol[e];
        float xv = x[(size_t)c * Fin + i];
        f32x4 wv = *(const f32x4*)(ew4 + 4 * e);
        int4 kv = *(const int4*)(ek4 + 4 * e);
        plane[kv.x * Fin + i] += wv[0] * xv;
        plane[kv.y * Fin + i] += wv[1] * xv;
        plane[kv.z * Fin + i] += wv[2] * xv;
        plane[kv.w * Fin + i] += wv[3] * xv;
      }
    }
    __syncthreads();
    if (r < NND) {
      float dinv = deginv[r];
      int tot = 26 * Fin;
      float* base = lds + group * 4 * nb4;
      for (int tt = t2; tt < tot; tt += tpr) {
        float v;
        if (tt < nb4)
          v = (base[tt] + base[nb4 + tt] + base[2 * nb4 + tt] + base[3 * nb4 + tt]) * dinv;
        else
          v = x[(size_t)r * Fin + (tt - nb4)];
        unsigned short h, l;
        split2(v, h, l);
        Bh[(size_t)r * tot + tt] = h;
        Bl[(size_t)r * tot + tt] = l;
      }
    }
    __syncthreads();
  }
}

// ---- phase: final GEMM (128x128, BK=64 dbuf, rotation swizzle) ----
// MODE 0: online-softmax partials (m,s); MODE 1: coalesced logit - lse stores.
template <int MODE>
__device__ void final_gemm(char* smem, const unsigned short* A, const unsigned short* Bt,
                           const float* bias, const float* lsep, float* outp,
                           int bid, int nbk, int tid) {
  const int M = NND, N = NND;
  auto lds = reinterpret_cast<unsigned short(*)[2][8192]>(smem);
  int w = tid >> 6, l = tid & 63;
  int wm = w >> 1, wn = w & 1;
  int g = l >> 4, r = l & 15;

  for (int t0 = bid; t0 < 54 * 54; t0 += nbk) {
    int by = t0 / 54, bx = t0 - by * 54;
    int row0 = by * 128, col0 = bx * 128;

    auto STAGE = [&](int buf, int kb) {
#pragma unroll
      for (int it = 0; it < 4; ++it) {
        int idx = it * 256 + tid;
        int rr = idx >> 3, pos = idx & 7;
        int c = (pos - rr) & 7;
        int gra = row0 + rr; if (gra >= M) gra = M - 1;
        int grb = col0 + rr; if (grb >= N) grb = N - 1;
        gload_lds16(A + (size_t)gra * 256 + kb + c * 8, &lds[buf][0][(it * 256 + w * 64) * 8]);
        gload_lds16(Bt + (size_t)grb * 256 + kb + c * 8, &lds[buf][1][(it * 256 + w * 64) * 8]);
      }
    };

    f32x4 acc[4][4];
#pragma unroll
    for (int mi = 0; mi < 4; ++mi)
#pragma unroll
      for (int ni = 0; ni < 4; ++ni)
#pragma unroll
        for (int q = 0; q < 4; ++q) acc[mi][ni][q] = 0.f;

    STAGE(0, 0);
    __syncthreads();
#pragma unroll
    for (int ks = 0; ks < 4; ++ks) {
      int buf = ks & 1;
      if (ks < 3) STAGE(buf ^ 1, (ks + 1) * 64);
#pragma unroll
      for (int sub = 0; sub < 2; ++sub) {
        bf16x8 fa[4], fb[4];
#pragma unroll
        for (int mi = 0; mi < 4; ++mi) {
          int rAi = wm * 64 + mi * 16 + r;
          fa[mi] = *(const bf16x8*)&lds[buf][0][rAi * 64 + ((g + 4 * sub + rAi) & 7) * 8];
        }
#pragma unroll
        for (int ni = 0; ni < 4; ++ni) {
          int rBi = wn * 64 + ni * 16 + r;
          fb[ni] = *(const bf16x8*)&lds[buf][1][rBi * 64 + ((g + 4 * sub + rBi) & 7) * 8];
        }
#pragma unroll
        for (int mi = 0; mi < 4; ++mi)
#pragma unroll
          for (int ni = 0; ni < 4; ++ni)
            acc[mi][ni] = __builtin_amdgcn_mfma_f32_16x16x32_bf16(fb[ni], fa[mi], acc[mi][ni], 0, 0, 0);
      }
      __syncthreads();
    }

    if (MODE == 0) {
      float bb[4][4];
#pragma unroll
      for (int ni = 0; ni < 4; ++ni) {
        int gc0 = col0 + wn * 64 + ni * 16 + g * 4;
#pragma unroll
        for (int q = 0; q < 4; ++q)
          bb[ni][q] = (gc0 + q < N) ? bias[gc0 + q] : 0.f;
      }
#pragma unroll
      for (int mi = 0; mi < 4; ++mi) {
        int gr = row0 + wm * 64 + mi * 16 + r;
        float vv[4][4];
        float mloc = -3e38f;
#pragma unroll
        for (int ni = 0; ni < 4; ++ni) {
          int gc0 = col0 + wn * 64 + ni * 16 + g * 4;
#pragma unroll
          for (int q = 0; q < 4; ++q) {
            float v = (gc0 + q < N) ? (acc[mi][ni][q] + bb[ni][q]) : -3e38f;
            vv[ni][q] = v;
            mloc = fmaxf(mloc, v);
          }
        }
        float sloc = 0.f;
#pragma unroll
        for (int ni = 0; ni < 4; ++ni) {
          int gc0 = col0 + wn * 64 + ni * 16 + g * 4;
#pragma unroll
          for (int q = 0; q < 4; ++q)
            if (gc0 + q < N) sloc += __expf(vv[ni][q] - mloc);
        }
#pragma unroll
        for (int off = 16; off < 64; off <<= 1) {
          float mo = __shfl_xor(mloc, off);
          float so = __shfl_xor(sloc, off);
          float mn = fmaxf(mloc, mo);
          sloc = sloc * __expf(mloc - mn) + so * __expf(mo - mn);
          mloc = mn;
        }
        if (g == 0 && gr < M) {
          int hb = bx * 2 + wn;
          *(float2*)(outp + 2 * ((size_t)hb * M + gr)) = make_float2(mloc, sloc);
        }
      }
    } else {
      float* fsc = (float*)smem;
      float* wbase = fsc + w * 4096;
#pragma unroll
      for (int mi = 0; mi < 4; ++mi) {
        int rr = mi * 16 + r;
#pragma unroll
        for (int ni = 0; ni < 4; ++ni) {
          int u = (ni * 4 + g + rr) & 15;
          *(f32x4*)(wbase + rr * 64 + u * 4) = acc[mi][ni];
        }
      }
      __syncthreads();
#pragma unroll
      for (int tt = 0; tt < 16; ++tt) {
        int unit = tt * 256 + tid;
        int rowi = unit >> 5, ch = unit & 31;
        int gr = row0 + rowi;
        if (gr < M) {
          int reg = ((rowi >> 6) << 1) + (ch >> 4);
          int rr = rowi & 63;
          int u = ((ch & 15) + rr) & 15;
          f32x4 v = *(const f32x4*)(fsc + reg * 4096 + rr * 64 + u * 4);
          float L = lsep[gr];
          int gc0 = col0 + ch * 4;
          if (gc0 + 4 <= N) {
            f32x4 bv = *(const f32x4*)(bias + gc0);
#pragma unroll
            for (int q = 0; q < 4; ++q) v[q] = v[q] + bv[q] - L;
            *(f32x4*)(outp + (size_t)gr * N + gc0) = v;
          } else {
#pragma unroll
            for (int q = 0; q < 4; ++q)
              if (gc0 + q < N) outp[(size_t)gr * N + gc0 + q] = v[q] + bias[gc0 + q] - L;
          }
        }
      }
      __syncthreads();
    }
  }
}

// ==== the mega kernel: whole network, one cooperative launch ====
__global__ __launch_bounds__(256, 2) void mega_kernel(MP p) {
  cg::grid_group grid = cg::this_grid();
  __shared__ __align__(16) char smem[65536];
  const int bid = blockIdx.x;
  const int nbk = gridDim.x;
  const int tid = threadIdx.x;
  const int gidx = bid * 256 + tid;
  const int gstride = nbk * 256;
  const int* erow = p.ei;
  const int* ecol = p.ei + NED;

  // ph0: zero deg
  for (int i = gidx; i < NND; i += gstride) p.deg[i] = 0;
  grid.sync();

  // ph1: edge prep
  for (int e = gidx; e < NED; e += gstride) {
    float p0 = p.pseudo[2 * e + 0] * 4.0f;
    float p1 = p.pseudo[2 * e + 1] * 4.0f;
    int i0 = (int)floorf(p0); i0 = i0 < 0 ? 0 : (i0 > 3 ? 3 : i0);
    int i1 = (int)floorf(p1); i1 = i1 < 0 ? 0 : (i1 > 3 ? 3 : i1);
    float f0 = p0 - (float)i0, f1 = p1 - (float)i1;
    p.ew[4 * e + 0] = (1.f - f0) * (1.f - f1);
    p.ew[4 * e + 1] = f0 * (1.f - f1);
    p.ew[4 * e + 2] = (1.f - f0) * f1;
    p.ew[4 * e + 3] = f0 * f1;
    int b = i0 + 5 * i1;
    p.ek[4 * e + 0] = b; p.ek[4 * e + 1] = b + 1;
    p.ek[4 * e + 2] = b + 5; p.ek[4 * e + 3] = b + 6;
    atomicAdd(&p.deg[erow[e]], 1);
  }
  grid.sync();

  // ph2: block 0 scans; others do prep tiles
  if (bid == 0) {
    int* part = (int*)smem;
    const int CH = (NND + 255) >> 8;
    int base = tid * CH;
    int s = 0;
    for (int j = 0; j < CH; ++j) { int i = base + j; if (i < NND) s += p.deg[i]; }
    part[tid] = s;
    __syncthreads();
    for (int off = 1; off < 256; off <<= 1) {
      int v = (tid >= off) ? part[tid - off] : 0;
      __syncthreads();
      part[tid] += v;
      __syncthreads();
    }
    int run = (tid == 0) ? 0 : part[tid - 1];
    for (int j = 0; j < CH; ++j) {
      int i = base + j;
      if (i < NND) {
        p.rowptr[i] = run;
        p.cursor[i] = run;
        int d = p.deg[i];
        p.deginv[i] = 1.0f / fmaxf((float)d, 1.0f);
        run += d;
      }
    }
    if (tid == 255) p.rowptr[NND] = part[255];
  } else {
    for (int vt = bid - 1; vt < 5712; vt += nbk - 1) {
      prep_tile(smem, p, vt, tid);
      __syncthreads();
    }
  }
  grid.sync();

  // ph3: csr fill
  for (int e = gidx; e < NED; e += gstride) {
    int slot = atomicAdd(&p.cursor[erow[e]], 1);
    p.csr[slot] = e;
  }
  grid.sync();

  // ph4: stage0 h0 = elu(x @ W_lin + b_lin)
  mid_gemm<16, 0>(smem, p.xh, p.xl, p.Wth, p.Wtl, p.b_lin, p.h0, nullptr, nullptr,
                  544, 16, 1, bid, nbk, tid);
  grid.sync();
  // ph5: b_build layer 1
  b_build_phase(smem, p.h0, ecol, p.ew, p.ek, p.rowptr, p.csr, p.deginv, p.Bh, p.Bl,
                16, bid, nbk, tid);
  grid.sync();
  // ph6: layer 1 GEMM fused
  mid_gemm<32, 0>(smem, p.Bh, p.Bl, p.Wth + 8704, p.Wtl + 8704, p.bi1, p.h1, nullptr, nullptr,
                  416, 32, 1, bid, nbk, tid);
  grid.sync();
  // ph7: b_build layer 2
  b_build_phase(smem, p.h1, ecol, p.ew, p.ek, p.rowptr, p.csr, p.deginv, p.Bh, p.Bl,
                32, bid, nbk, tid);
  grid.sync();
  // ph8: layer 2 GEMM split-K
  mid_gemm<64, 3>(smem, p.Bh, p.Bl, p.Wth + 22016, p.Wtl + 22016, nullptr, nullptr, nullptr,
                  p.Pbuf, 832, 64, 4, bid, nbk, tid);
  grid.sync();
  // ph9: combine -> h2
  combine_phase(p.Pbuf, p.bi2, p.h2, nullptr, nullptr, 64, 4, gidx, gstride);
  grid.sync();
  // ph10: b_build layer 3
  b_build_phase(smem, p.h2, ecol, p.ew, p.ek, p.rowptr, p.csr, p.deginv, p.Bh, p.Bl,
                64, bid, nbk, tid);
  grid.sync();
  // ph11: layer 3 GEMM split-K
  mid_gemm<128, 3>(smem, p.Bh, p.Bl, p.Wth + 75264, p.Wtl + 75264, nullptr, nullptr, nullptr,
                   p.Pbuf, 1664, 128, 4, bid, nbk, tid);
  grid.sync();
  // ph12: combine -> h3 hi/lo planes
  combine_phase(p.Pbuf, p.bi3, nullptr, p.h3h, p.h3l, 128, 4, gidx, gstride);
  grid.sync();
  // ph13: stage4 h4 = elu(h3 @ W1 + b1) -> bf16
  mid_gemm<128, 2>(smem, p.h3h, p.h3l, p.Wth + 288256, p.Wtl + 288256, p.b1, nullptr, p.h4b,
                   nullptr, 128, 256, 1, bid, nbk, tid);
  grid.sync();
  // ph14: pass A -> stats
  final_gemm<0>(smem, p.h4b, p.W2t, p.b2, nullptr, p.stats, bid, nbk, tid);
  grid.sync();
  // ph15: lse
  for (int row = gidx; row < NND; row += gstride) {
    float m = -3e38f, s = 0.f;
    for (int hb = 0; hb < 108; ++hb) {
      float2 v = *(const float2*)(p.stats + 2 * ((size_t)hb * NND + row));
      float mn = fmaxf(m, v.x);
      s = s * __expf(m - mn) + v.y * __expf(v.x - mn);
      m = mn;
    }
    p.lse[row] = m + logf(s);
  }
  grid.sync();
  // ph16: pass C -> output
  final_gemm<1>(smem, p.h4b, p.W2t, p.b2, p.lse, p.outp, bid, nbk, tid);
}

extern "C" void kernel_launch(void* const* d_in, const int* in_sizes, int n_in,
                              void* d_out, int out_size, void* d_ws, size_t ws_size,
                              hipStream_t stream) {
  MP p;
  p.x      = (const float*)d_in[0];
  p.ei     = (const int*)d_in[1];
  p.pseudo = (const float*)d_in[2];
  p.W_lin  = (const float*)d_in[3];
  p.b_lin  = (const float*)d_in[4];
  p.w1  = (const float*)d_in[5];  p.r1 = (const float*)d_in[6];  p.bi1 = (const float*)d_in[7];
  p.w2  = (const float*)d_in[8];  p.r2 = (const float*)d_in[9];  p.bi2 = (const float*)d_in[10];
  p.w3  = (const float*)d_in[11]; p.r3 = (const float*)d_in[12]; p.bi3 = (const float*)d_in[13];
  p.W1  = (const float*)d_in[14]; p.b1 = (const float*)d_in[15];
  p.W2  = (const float*)d_in[16]; p.b2 = (const float*)d_in[17];

  char* scratch = (char*)d_out;
  size_t off = 0;
  auto alloc = [&](size_t bytes) -> void* {
    void* q = scratch + off;
    off = (off + bytes + 255) & ~(size_t)255;
    return q;
  };
  p.Bh  = (unsigned short*)alloc((size_t)NND * 1664 * 2);
  p.Bl  = (unsigned short*)alloc((size_t)NND * 1664 * 2);
  p.h0  = (float*)alloc((size_t)NND * 16 * 4);
  p.h1  = (float*)alloc((size_t)NND * 32 * 4);
  p.h2  = (float*)alloc((size_t)NND * 64 * 4);
  p.h3h = (unsigned short*)alloc((size_t)NND * 128 * 2);
  p.h3l = (unsigned short*)alloc((size_t)NND * 128 * 2);
  p.xh  = (unsigned short*)alloc((size_t)NND * 544 * 2);
  p.xl  = (unsigned short*)alloc((size_t)NND * 544 * 2);
  p.Wth = (unsigned short*)alloc((size_t)321024 * 2);
  p.Wtl = (unsigned short*)alloc((size_t)321024 * 2);
  p.Pbuf  = (float*)alloc((size_t)4 * NND * 128 * 4);
  p.stats = (float*)alloc((size_t)108 * NND * 2 * 4);
  p.ew  = (float*)alloc((size_t)NED * 4 * 4);
  p.ek  = (int*)alloc((size_t)NED * 4 * 4);
  p.deg = (int*)alloc((size_t)NND * 4);
  p.deginv = (float*)alloc((size_t)NND * 4);
  p.rowptr = (int*)alloc((size_t)(NND + 1) * 4);
  p.cursor = (int*)alloc((size_t)NND * 4);
  p.csr = (int*)alloc((size_t)NED * 4);
  p.outp = (float*)d_out;

  p.h4b = (unsigned short*)d_ws;
  p.W2t = (unsigned short*)((char*)d_ws + (size_t)NND * 256 * 2);
  p.lse = (float*)((char*)d_ws + (size_t)NND * 256 * 4);

  int occ = 0;
  hipOccupancyMaxActiveBlocksPerMultiprocessor(&occ, (const void*)mega_kernel, 256, 0);
  if (occ < 1) occ = 1;
  if (occ > 2) occ = 2;
  dim3 grid(occ * 256);
  void* args[] = {(void*)&p};
  hipLaunchCooperativeKernel((const void*)mega_kernel, grid, dim3(256), args, 0, stream);

  (void)in_sizes; (void)n_in; (void)out_size; (void)ws_size;
}

// Round 10
// 306.252 us; speedup vs baseline: 2.9451x; 2.9451x over previous
//
#include <hip/hip_runtime.h>
#include <hip/hip_bf16.h>

#define NND 6890
#define NED 41340

typedef __bf16 bf16x8 __attribute__((ext_vector_type(8)));
typedef float f32x4 __attribute__((ext_vector_type(4)));
typedef unsigned short u16x4 __attribute__((ext_vector_type(4)));

__device__ inline unsigned short f32_bf16(float f) {
  unsigned int u = __float_as_uint(f);
  unsigned int r = (u + 0x7FFFu + ((u >> 16) & 1u)) >> 16;
  return (unsigned short)r;
}
__device__ inline void split2(float v, unsigned short& hi, unsigned short& lo) {
  unsigned short h = f32_bf16(v);
  float hf = __uint_as_float((unsigned int)h << 16);
  hi = h;
  lo = f32_bf16(v - hf);
}
__device__ inline float elu_f(float v) { return v > 0.f ? v : (expf(v) - 1.f); }

__device__ __forceinline__ void gload_lds16(const void* g, void* l) {
  __builtin_amdgcn_global_load_lds((const __attribute__((address_space(1))) void*)g,
                                   (__attribute__((address_space(3))) void*)l, 16, 0, 0);
}

__global__ void edge_prep_kernel(const int* __restrict__ erow, const float* __restrict__ pseudo,
                                 float* __restrict__ ew, int* __restrict__ ek,
                                 int* __restrict__ deg, int E) {
  int e = blockIdx.x * blockDim.x + threadIdx.x;
  if (e >= E) return;
  float p0 = pseudo[2 * e + 0] * 4.0f;
  float p1 = pseudo[2 * e + 1] * 4.0f;
  int i0 = (int)floorf(p0); i0 = i0 < 0 ? 0 : (i0 > 3 ? 3 : i0);
  int i1 = (int)floorf(p1); i1 = i1 < 0 ? 0 : (i1 > 3 ? 3 : i1);
  float f0 = p0 - (float)i0, f1 = p1 - (float)i1;
  ew[4 * e + 0] = (1.f - f0) * (1.f - f1);
  ew[4 * e + 1] = f0 * (1.f - f1);
  ew[4 * e + 2] = (1.f - f0) * f1;
  ew[4 * e + 3] = f0 * f1;
  int b = i0 + 5 * i1;
  ek[4 * e + 0] = b; ek[4 * e + 1] = b + 1; ek[4 * e + 2] = b + 5; ek[4 * e + 3] = b + 6;
  atomicAdd(&deg[erow[e]], 1);
}

__global__ void scan_kernel(const int* __restrict__ deg, int* __restrict__ rowptr,
                            int* __restrict__ cursor, float* __restrict__ deginv, int n) {
  __shared__ int part[1024];
  int t = threadIdx.x;
  int CH = (n + 1023) >> 10;
  int base = t * CH;
  int s = 0;
  for (int j = 0; j < CH; ++j) { int i = base + j; if (i < n) s += deg[i]; }
  part[t] = s;
  __syncthreads();
  for (int off = 1; off < 1024; off <<= 1) {
    int v = (t >= off) ? part[t - off] : 0;
    __syncthreads();
    part[t] += v;
    __syncthreads();
  }
  int run = (t == 0) ? 0 : part[t - 1];
  for (int j = 0; j < CH; ++j) {
    int i = base + j;
    if (i < n) {
      rowptr[i] = run; cursor[i] = run;
      int d = deg[i];
      deginv[i] = 1.0f / fmaxf((float)d, 1.0f);
      run += d;
    }
  }
  if (t == 1023) rowptr[n] = part[1023];
}

__global__ void csr_fill_kernel(const int* __restrict__ erow, int* __restrict__ cursor,
                                int* __restrict__ csr, int E) {
  int e = blockIdx.x * blockDim.x + threadIdx.x;
  if (e >= E) return;
  int slot = atomicAdd(&cursor[erow[e]], 1);
  csr[slot] = e;
}

// One prep kernel: [0,323) weight splits; [323,3984) x split; [3984,5712) W2^T cast.
__global__ void prep_all_kernel(const float* __restrict__ W_lin, const float* __restrict__ w1,
                                const float* __restrict__ r1, const float* __restrict__ w2,
                                const float* __restrict__ r2, const float* __restrict__ w3,
                                const float* __restrict__ r3, const float* __restrict__ W1,
                                const float* __restrict__ x, const float* __restrict__ W2,
                                unsigned short* __restrict__ Th, unsigned short* __restrict__ Tl,
                                unsigned short* __restrict__ xh, unsigned short* __restrict__ xl,
                                unsigned short* __restrict__ W2t) {
  int b = blockIdx.x;
  int tid = threadIdx.x;
  if (b < 323) {
    const int tstart[9] = {0, 17, 30, 31, 81, 83, 283, 291, 323};
    const int jK[8]    = {544, 400, 16, 800, 32, 1600, 64, 128};
    const int jF[8]    = {16, 32, 32, 64, 64, 128, 128, 256};
    const int jldt[8]  = {544, 416, 416, 832, 832, 1664, 1664, 128};
    const int jkoff[8] = {0, 0, 400, 0, 800, 0, 1600, 0};
    const int jdst[8]  = {0, 8704, 8704, 22016, 22016, 75264, 75264, 288256};
    int job = 0;
    while (job < 7 && b >= tstart[job + 1]) ++job;
    int t = b - tstart[job];
    int fxc = (jF[job] + 31) >> 5;
    int kt = t / fxc, ft = t % fxc;
    const float* src;
    switch (job) {
      case 0: src = W_lin; break;
      case 1: src = w1; break;
      case 2: src = r1; break;
      case 3: src = w2; break;
      case 4: src = r2; break;
      case 5: src = w3; break;
      case 6: src = r3; break;
      default: src = W1; break;
    }
    int K = jK[job], F = jF[job], ldt = jldt[job], koff = jkoff[job];
    unsigned short* th = Th + jdst[job];
    unsigned short* tl = Tl + jdst[job];
    int k0 = kt * 32, c0 = ft * 32;
    __shared__ float tbuf[32][33];
    int tx = tid & 31, ty = tid >> 5;
    for (int j = ty; j < 32; j += 8) {
      int gk = k0 + j, gc = c0 + tx;
      tbuf[j][tx] = (gk < K && gc < F) ? src[(size_t)gk * F + gc] : 0.f;
    }
    __syncthreads();
    for (int j = ty; j < 32; j += 8) {
      int gc = c0 + j, gk = k0 + tx;
      if (gc < F && gk < K) {
        unsigned short h, lo2;
        split2(tbuf[tx][j], h, lo2);
        th[(size_t)gc * ldt + koff + gk] = h;
        tl[(size_t)gc * ldt + koff + gk] = lo2;
      }
    }
  } else if (b < 3984) {
    int i = (b - 323) * 256 + tid;   // f32x4 units, n4 = NND*136
    if (i < NND * 136) {
      f32x4 v = *(const f32x4*)(x + 4 * (size_t)i);
      u16x4 h, l;
#pragma unroll
      for (int j = 0; j < 4; ++j) {
        unsigned short hh, ll;
        split2(v[j], hh, ll);
        h[j] = hh; l[j] = ll;
      }
      *(u16x4*)(xh + 4 * (size_t)i) = h;
      *(u16x4*)(xl + 4 * (size_t)i) = l;
    }
  } else {
    int t = b - 3984;
    int c0 = (t % 216) * 32, k0 = (t / 216) * 32;
    __shared__ float tb2[32][33];
    int tx = tid & 31, ty = tid >> 5;
    for (int j = ty; j < 32; j += 8) {
      int gk = k0 + j, gc = c0 + tx;
      tb2[j][tx] = (gk < 256 && gc < NND) ? W2[(size_t)gk * NND + gc] : 0.f;
    }
    __syncthreads();
    for (int j = ty; j < 32; j += 8) {
      int gc = c0 + j, gk = k0 + tx;
      if (gc < NND && gk < 256) W2t[(size_t)gc * 256 + gk] = f32_bf16(tb2[tx][j]);
    }
  }
}

// B-row build, atomic-free: 4 edge-phase LDS planes; outputs bf16 hi/lo planes.
__global__ void b_build_kernel(const float* __restrict__ x, const int* __restrict__ ecol,
                               const float* __restrict__ ew4, const int* __restrict__ ek4,
                               const int* __restrict__ rowptr, const int* __restrict__ csr,
                               const float* __restrict__ deginv,
                               unsigned short* __restrict__ Bh, unsigned short* __restrict__ Bl,
                               int Fin) {
  extern __shared__ float lds[];  // 4 planes x 25*Fin floats
  int r = blockIdx.x;
  int T = blockDim.x;  // 4*Fin
  int tid = threadIdx.x;
  int nb = 25 * Fin;
  int j = tid / Fin;
  int i = tid - j * Fin;
  float* plane = lds + j * nb;
  for (int t = tid; t < 4 * nb; t += T) lds[t] = 0.f;
  __syncthreads();
  int p0 = rowptr[r], p1 = rowptr[r + 1];
  for (int p = p0 + j; p < p1; p += 4) {
    int e = csr[p];
    int c = ecol[e];
    float xv = x[(size_t)c * Fin + i];
    f32x4 wv = *(const f32x4*)(ew4 + 4 * e);
    int4 kv = *(const int4*)(ek4 + 4 * e);
    plane[kv.x * Fin + i] += wv[0] * xv;
    plane[kv.y * Fin + i] += wv[1] * xv;
    plane[kv.z * Fin + i] += wv[2] * xv;
    plane[kv.w * Fin + i] += wv[3] * xv;
  }
  __syncthreads();
  float dinv = deginv[r];
  int tot = nb + Fin;  // = 26*Fin = Kd
  for (int t = tid; t < tot; t += T) {
    float v;
    if (t < nb)
      v = (lds[t] + lds[nb + t] + lds[2 * nb + t] + lds[3 * nb + t]) * dinv;
    else
      v = x[(size_t)r * Fin + (t - nb)];
    unsigned short h, l;
    split2(v, h, l);
    Bh[(size_t)r * tot + t] = h;
    Bl[(size_t)r * tot + t] = l;
  }
}

// Partial GEMM (bf16x3) over K-slice z: P[z][M][F] = A @ W.
// A, W pre-split bf16 planes; staging via global_load_lds with per-row
// 4-chunk rotation (bank-even). 64-row A tile, BN-col W tile, BK=32.
template <int BN>
__global__ __launch_bounds__(256) void gemm_x3_partial_kernel(
    const unsigned short* __restrict__ Ah, const unsigned short* __restrict__ Al,
    const unsigned short* __restrict__ Wh, const unsigned short* __restrict__ Wl,
    float* __restrict__ P, int M, int Kd, int F, int KS) {
  constexpr int AE = 64 * 32;   // elements per A plane tile
  constexpr int WE = BN * 32;
  __shared__ __align__(16) unsigned short lds[2][2 * AE + 2 * WE];
  int tid = threadIdx.x;
  int wave = tid >> 6, lane = tid & 63;
  int g = lane >> 4, r = lane & 15;
  int row0 = blockIdx.y * 64;
  int col0 = blockIdx.x * BN;
  int z = blockIdx.z;
  int nt = Kd >> 5;
  int ta = z * nt / KS, tb = (z + 1) * nt / KS;

  auto STAGE = [&](int buf, int kb) {
    {
      int rr = tid >> 2, pos = tid & 3;
      int c = (pos - rr) & 3;
      int gra = row0 + rr; if (gra >= M) gra = M - 1;
      size_t so = (size_t)gra * Kd + kb + c * 8;
      gload_lds16(Ah + so, &lds[buf][wave * 512]);
      gload_lds16(Al + so, &lds[buf][AE + wave * 512]);
    }
#pragma unroll
    for (int it = 0; it < (4 * BN + 255) / 256; ++it) {
      int idx = it * 256 + tid;
      if (idx < 4 * BN) {
        int rr = idx >> 2, pos = idx & 3;
        int c = (pos - rr) & 3;
        size_t so = (size_t)(col0 + rr) * Kd + kb + c * 8;
        gload_lds16(Wh + so, &lds[buf][2 * AE + (it * 256 + wave * 64) * 8]);
        gload_lds16(Wl + so, &lds[buf][2 * AE + WE + (it * 256 + wave * 64) * 8]);
      }
    }
  };

  constexpr int NF = BN / 16;
  f32x4 acc[NF];
#pragma unroll
  for (int n = 0; n < NF; ++n)
#pragma unroll
    for (int q = 0; q < 4; ++q) acc[n][q] = 0.f;

  int n = tb - ta;
  int rA = wave * 16 + r;
  int aoff = rA * 32 + ((g + rA) & 3) * 8;

  STAGE(0, ta * 32);
  __syncthreads();
  for (int tt = 0; tt < n; ++tt) {
    int buf = tt & 1;
    if (tt + 1 < n) STAGE(buf ^ 1, (ta + tt + 1) * 32);
    bf16x8 fah = *(const bf16x8*)&lds[buf][aoff];
    bf16x8 fal = *(const bf16x8*)&lds[buf][AE + aoff];
#pragma unroll
    for (int nn = 0; nn < NF; ++nn) {
      int rW = nn * 16 + r;
      int woff = rW * 32 + ((g + rW) & 3) * 8;
      bf16x8 fbh = *(const bf16x8*)&lds[buf][2 * AE + woff];
      bf16x8 fbl = *(const bf16x8*)&lds[buf][2 * AE + WE + woff];
      acc[nn] = __builtin_amdgcn_mfma_f32_16x16x32_bf16(fah, fbh, acc[nn], 0, 0, 0);
      acc[nn] = __builtin_amdgcn_mfma_f32_16x16x32_bf16(fal, fbh, acc[nn], 0, 0, 0);
      acc[nn] = __builtin_amdgcn_mfma_f32_16x16x32_bf16(fah, fbl, acc[nn], 0, 0, 0);
    }
    __syncthreads();
  }
#pragma unroll
  for (int nn = 0; nn < NF; ++nn) {
    int gc = col0 + nn * 16 + r;
#pragma unroll
    for (int q = 0; q < 4; ++q) {
      int gr = row0 + wave * 16 + g * 4 + q;
      if (gr < M) P[((size_t)z * M + gr) * F + gc] = acc[nn][q];
    }
  }
}

// out = elu(sum_z P[z] + bias); f32, bf16, or hi/lo-plane output
__global__ __launch_bounds__(256) void combine_elu_kernel(
    const float* __restrict__ P, const float* __restrict__ bias,
    float* __restrict__ outF, unsigned short* __restrict__ outB,
    unsigned short* __restrict__ outH, unsigned short* __restrict__ outL,
    int M, int F, int KS) {
  int i4 = blockIdx.x * 256 + threadIdx.x;
  int fv = F >> 2;
  int total = M * fv;
  if (i4 >= total) return;
  int gr = i4 / fv, c4 = (i4 - gr * fv) * 4;
  f32x4 s = {0.f, 0.f, 0.f, 0.f};
  for (int z = 0; z < KS; ++z)
    s += *(const f32x4*)(P + ((size_t)z * M + gr) * F + c4);
  f32x4 bv = *(const f32x4*)(bias + c4);
#pragma unroll
  for (int j = 0; j < 4; ++j) s[j] = elu_f(s[j] + bv[j]);
  if (outH) {
    u16x4 h, l;
#pragma unroll
    for (int j = 0; j < 4; ++j) {
      unsigned short hh, ll;
      split2(s[j], hh, ll);
      h[j] = hh; l[j] = ll;
    }
    *(u16x4*)(outH + (size_t)gr * F + c4) = h;
    *(u16x4*)(outL + (size_t)gr * F + c4) = l;
  } else if (outB) {
    u16x4 o;
#pragma unroll
    for (int j = 0; j < 4; ++j) o[j] = f32_bf16(s[j]);
    *(u16x4*)(outB + (size_t)gr * F + c4) = o;
  } else {
    *(f32x4*)(outF + (size_t)gr * F + c4) = s;
  }
}

// Final layer GEMM: 128x128 tile, BK=32 double-buffered (LDS 32 KB -> ~5 blk/CU),
// per-row 4-chunk rotation (bank-even frag reads). FP order identical to BK=64 ver.
// MODE 0: online-softmax partials (m,s) per (row, 64-col wave half).
// MODE 1: two-round LDS stash (32 KB each), coalesced f32x4 stores of logit+bias-lse.
template <int MODE>
__global__ __launch_bounds__(256) void gemm_final_kernel(
    const unsigned short* __restrict__ A, const unsigned short* __restrict__ Bt,
    const float* __restrict__ bias, const float* __restrict__ lse,
    float* __restrict__ outp, int M, int N) {
  __shared__ __align__(16) unsigned short lds[2][2][4096];  // [buf][A/B][128*32] = 32 KB
  int tid = threadIdx.x;
  int w = tid >> 6, l = tid & 63;
  int row0 = blockIdx.y * 128, col0 = blockIdx.x * 128;

  auto STAGE = [&](int buf, int kb) {
#pragma unroll
    for (int it = 0; it < 2; ++it) {
      int idx = it * 256 + tid;            // chunk id 0..511 (128 rows x 4)
      int rr = idx >> 2, pos = idx & 3;
      int c = (pos - rr) & 3;
      int gra = row0 + rr; if (gra >= M) gra = M - 1;
      int grb = col0 + rr; if (grb >= N) grb = N - 1;
      gload_lds16(A + (size_t)gra * 256 + kb + c * 8, &lds[buf][0][(it * 256 + w * 64) * 8]);
      gload_lds16(Bt + (size_t)grb * 256 + kb + c * 8, &lds[buf][1][(it * 256 + w * 64) * 8]);
    }
  };

  int wm = w >> 1, wn = w & 1;
  int g = l >> 4, r = l & 15;

  f32x4 acc[4][4];
#pragma unroll
  for (int mi = 0; mi < 4; ++mi)
#pragma unroll
    for (int ni = 0; ni < 4; ++ni)
#pragma unroll
      for (int q = 0; q < 4; ++q) acc[mi][ni][q] = 0.f;

  STAGE(0, 0);
  __syncthreads();
#pragma unroll
  for (int ks = 0; ks < 8; ++ks) {
    int buf = ks & 1;
    if (ks < 7) STAGE(buf ^ 1, (ks + 1) * 32);
    bf16x8 fa[4], fb[4];
#pragma unroll
    for (int mi = 0; mi < 4; ++mi) {
      int rA = wm * 64 + mi * 16 + r;
      fa[mi] = *(const bf16x8*)&lds[buf][0][rA * 32 + ((g + rA) & 3) * 8];
    }
#pragma unroll
    for (int ni = 0; ni < 4; ++ni) {
      int rB = wn * 64 + ni * 16 + r;
      fb[ni] = *(const bf16x8*)&lds[buf][1][rB * 32 + ((g + rB) & 3) * 8];
    }
#pragma unroll
    for (int mi = 0; mi < 4; ++mi)
#pragma unroll
      for (int ni = 0; ni < 4; ++ni)
        acc[mi][ni] = __builtin_amdgcn_mfma_f32_16x16x32_bf16(fb[ni], fa[mi], acc[mi][ni], 0, 0, 0);
    __syncthreads();
  }

  if (MODE == 0) {
    float bb[4][4];
#pragma unroll
    for (int ni = 0; ni < 4; ++ni) {
      int gc0 = col0 + wn * 64 + ni * 16 + g * 4;
#pragma unroll
      for (int q = 0; q < 4; ++q)
        bb[ni][q] = (gc0 + q < N) ? bias[gc0 + q] : 0.f;
    }
#pragma unroll
    for (int mi = 0; mi < 4; ++mi) {
      int gr = row0 + wm * 64 + mi * 16 + r;
      float vv[4][4];
      float mloc = -3e38f;
#pragma unroll
      for (int ni = 0; ni < 4; ++ni) {
        int gc0 = col0 + wn * 64 + ni * 16 + g * 4;
#pragma unroll
        for (int q = 0; q < 4; ++q) {
          float v = (gc0 + q < N) ? (acc[mi][ni][q] + bb[ni][q]) : -3e38f;
          vv[ni][q] = v;
          mloc = fmaxf(mloc, v);
        }
      }
      float sloc = 0.f;
#pragma unroll
      for (int ni = 0; ni < 4; ++ni) {
        int gc0 = col0 + wn * 64 + ni * 16 + g * 4;
#pragma unroll
        for (int q = 0; q < 4; ++q)
          if (gc0 + q < N) sloc += __expf(vv[ni][q] - mloc);
      }
#pragma unroll
      for (int off = 16; off < 64; off <<= 1) {
        float mo = __shfl_xor(mloc, off);
        float so = __shfl_xor(sloc, off);
        float mn = fmaxf(mloc, mo);
        sloc = sloc * __expf(mloc - mn) + so * __expf(mo - mn);
        mloc = mn;
      }
      if (g == 0 && gr < M) {
        int hb = blockIdx.x * 2 + wn;
        *(float2*)(outp + 2 * ((size_t)hb * M + gr)) = make_float2(mloc, sloc);
      }
    }
  } else {
    // Two rounds: round p stashes acc[2p..2p+1] (64 rows x 128 cols = 32 KB),
    // then coalesced row-major stores with bias - lse.
    float* LBUF = (float*)&lds[0][0][0];  // 8192 floats
#pragma unroll
    for (int p = 0; p < 2; ++p) {
      __syncthreads();
#pragma unroll
      for (int mh = 0; mh < 2; ++mh) {
        int mi = 2 * p + mh;
        int lr = wm * 32 + mh * 16 + r;
#pragma unroll
        for (int ni = 0; ni < 4; ++ni) {
          int ch = wn * 16 + ni * 4 + g;        // 16B chunk 0..31 within 128-col row
          int u = (ch + lr) & 31;
          *(f32x4*)(LBUF + lr * 128 + u * 4) = acc[mi][ni];
        }
      }
      __syncthreads();
#pragma unroll
      for (int t = 0; t < 8; ++t) {
        int unit = t * 256 + tid;               // 2048 units: 64 rows x 32 chunks
        int lr = unit >> 5, ch = unit & 31;
        int gr = row0 + (lr >> 5) * 64 + p * 32 + ((lr >> 4) & 1) * 16 + (lr & 15);
        if (gr >= M) continue;
        int u = (ch + lr) & 31;
        f32x4 v = *(const f32x4*)(LBUF + lr * 128 + u * 4);
        float L = lse[gr];
        int gc0 = col0 + ch * 4;
        if (gc0 + 4 <= N) {
          f32x4 bv = *(const f32x4*)(bias + gc0);
#pragma unroll
          for (int q = 0; q < 4; ++q) v[q] = v[q] + bv[q] - L;
          *(f32x4*)(outp + (size_t)gr * N + gc0) = v;
        } else {
#pragma unroll
          for (int q = 0; q < 4; ++q)
            if (gc0 + q < N) outp[(size_t)gr * N + gc0 + q] = v[q] + bias[gc0 + q] - L;
        }
      }
    }
  }
}

// lse[row] = online-merge of NH (m,s) partials
__global__ __launch_bounds__(256) void lse_kernel(const float* __restrict__ stats,
                                                  float* __restrict__ lse, int M, int NH) {
  int row = blockIdx.x * 256 + threadIdx.x;
  if (row >= M) return;
  float m = -3e38f, s = 0.f;
  for (int hb = 0; hb < NH; ++hb) {
    float2 v = *(const float2*)(stats + 2 * ((size_t)hb * M + row));
    float mn = fmaxf(m, v.x);
    s = s * __expf(m - mn) + v.y * __expf(v.x - mn);
    m = mn;
  }
  lse[row] = m + logf(s);
}

extern "C" void kernel_launch(void* const* d_in, const int* in_sizes, int n_in,
                              void* d_out, int out_size, void* d_ws, size_t ws_size,
                              hipStream_t stream) {
  const int N = NND, E = NED;
  const float* x      = (const float*)d_in[0];
  const int*   ei     = (const int*)d_in[1];
  const float* pseudo = (const float*)d_in[2];
  const float* W_lin  = (const float*)d_in[3];
  const float* b_lin  = (const float*)d_in[4];
  const float* w1  = (const float*)d_in[5];
  const float* r1  = (const float*)d_in[6];
  const float* bi1 = (const float*)d_in[7];
  const float* w2  = (const float*)d_in[8];
  const float* r2  = (const float*)d_in[9];
  const float* bi2 = (const float*)d_in[10];
  const float* w3  = (const float*)d_in[11];
  const float* r3  = (const float*)d_in[12];
  const float* bi3 = (const float*)d_in[13];
  const float* W1  = (const float*)d_in[14];
  const float* b1  = (const float*)d_in[15];
  const float* W2  = (const float*)d_in[16];
  const float* b2  = (const float*)d_in[17];
  const int* erow = ei;
  const int* ecol = ei + E;

  // Scratch carved out of d_out (dead before pass C overwrites all of d_out)
  char* scratch = (char*)d_out;
  size_t off = 0;
  auto alloc = [&](size_t bytes) -> void* {
    void* p = scratch + off;
    off = (off + bytes + 255) & ~(size_t)255;
    return p;
  };
  unsigned short* Bh = (unsigned short*)alloc((size_t)N * 1664 * 2);
  unsigned short* Bl = (unsigned short*)alloc((size_t)N * 1664 * 2);
  float* h0     = (float*)alloc((size_t)N * 16 * 4);
  float* h1     = (float*)alloc((size_t)N * 32 * 4);
  float* h2     = (float*)alloc((size_t)N * 64 * 4);
  unsigned short* h3h = (unsigned short*)alloc((size_t)N * 128 * 2);
  unsigned short* h3l = (unsigned short*)alloc((size_t)N * 128 * 2);
  unsigned short* xh  = (unsigned short*)alloc((size_t)N * 544 * 2);
  unsigned short* xl  = (unsigned short*)alloc((size_t)N * 544 * 2);
  unsigned short* Wth = (unsigned short*)alloc((size_t)321024 * 2);
  unsigned short* Wtl = (unsigned short*)alloc((size_t)321024 * 2);
  float* Pbuf   = (float*)alloc((size_t)4 * N * 128 * 4);  // also fits 2*N*256
  float* stats  = (float*)alloc((size_t)108 * N * 2 * 4);
  float* ew     = (float*)alloc((size_t)E * 4 * 4);
  int*   ek     = (int*)alloc((size_t)E * 4 * 4);
  int*   deg    = (int*)alloc((size_t)N * 4);
  float* deginv = (float*)alloc((size_t)N * 4);
  int*   rowptr = (int*)alloc((size_t)(N + 1) * 4);
  int*   cursor = (int*)alloc((size_t)N * 4);
  int*   csr    = (int*)alloc((size_t)E * 4);

  // Buffers alive during pass C go in d_ws
  unsigned short* h4b = (unsigned short*)d_ws;                                 // N*256 bf16
  unsigned short* W2t = (unsigned short*)((char*)d_ws + (size_t)N * 256 * 2);  // N*256 bf16
  float* lse = (float*)((char*)d_ws + (size_t)N * 256 * 4);                    // N f32

  // ---- graph prep ----
  hipMemsetAsync(deg, 0, (size_t)N * 4, stream);
  edge_prep_kernel<<<(E + 255) / 256, 256, 0, stream>>>(erow, pseudo, ew, ek, deg, E);
  scan_kernel<<<1, 1024, 0, stream>>>(deg, rowptr, cursor, deginv, N);
  csr_fill_kernel<<<(E + 255) / 256, 256, 0, stream>>>(erow, cursor, csr, E);

  // ---- all splits/transposes in one wide launch ----
  prep_all_kernel<<<5712, 256, 0, stream>>>(W_lin, w1, r1, w2, r2, w3, r3, W1, x, W2,
                                            Wth, Wtl, xh, xl, W2t);

  auto cgrid = [](int M_, int F_) { return dim3((M_ * (F_ / 4) + 255) / 256); };

  // ---- stage 0: h0 = elu(x @ W_lin + b_lin) ----
  gemm_x3_partial_kernel<16><<<dim3(1, 108, 4), 256, 0, stream>>>(xh, xl, Wth + 0, Wtl + 0, Pbuf, N, 544, 16, 4);
  combine_elu_kernel<<<cgrid(N, 16), 256, 0, stream>>>(Pbuf, b_lin, h0, nullptr, nullptr, nullptr, N, 16, 4);

  // ---- spline layer 1 (16 -> 32), Kd = 416 ----
  b_build_kernel<<<N, 64, 4 * 25 * 16 * 4, stream>>>(h0, ecol, ew, ek, rowptr, csr, deginv, Bh, Bl, 16);
  gemm_x3_partial_kernel<32><<<dim3(1, 108, 4), 256, 0, stream>>>(Bh, Bl, Wth + 8704, Wtl + 8704, Pbuf, N, 416, 32, 4);
  combine_elu_kernel<<<cgrid(N, 32), 256, 0, stream>>>(Pbuf, bi1, h1, nullptr, nullptr, nullptr, N, 32, 4);

  // ---- spline layer 2 (32 -> 64), Kd = 832 ----
  b_build_kernel<<<N, 128, 4 * 25 * 32 * 4, stream>>>(h1, ecol, ew, ek, rowptr, csr, deginv, Bh, Bl, 32);
  gemm_x3_partial_kernel<64><<<dim3(1, 108, 4), 256, 0, stream>>>(Bh, Bl, Wth + 22016, Wtl + 22016, Pbuf, N, 832, 64, 4);
  combine_elu_kernel<<<cgrid(N, 64), 256, 0, stream>>>(Pbuf, bi2, h2, nullptr, nullptr, nullptr, N, 64, 4);

  // ---- spline layer 3 (64 -> 128), Kd = 1664 ----
  b_build_kernel<<<N, 256, 4 * 25 * 64 * 4, stream>>>(h2, ecol, ew, ek, rowptr, csr, deginv, Bh, Bl, 64);
  gemm_x3_partial_kernel<128><<<dim3(1, 108, 4), 256, 0, stream>>>(Bh, Bl, Wth + 75264, Wtl + 75264, Pbuf, N, 1664, 128, 4);
  combine_elu_kernel<<<cgrid(N, 128), 256, 0, stream>>>(Pbuf, bi3, nullptr, nullptr, h3h, h3l, N, 128, 4);

  // ---- stage 4: h4 = elu(h3 @ W1 + b1) -> bf16 ----
  gemm_x3_partial_kernel<128><<<dim3(2, 108, 2), 256, 0, stream>>>(h3h, h3l, Wth + 288256, Wtl + 288256, Pbuf, N, 128, 256, 2);
  combine_elu_kernel<<<cgrid(N, 256), 256, 0, stream>>>(Pbuf, b1, nullptr, h4b, nullptr, nullptr, N, 256, 2);

  // ---- pass A: softmax partials ----
  gemm_final_kernel<0><<<dim3(54, 54), 256, 0, stream>>>(h4b, W2t, b2, nullptr, stats, N, N);

  // ---- pass B: lse per row ----
  lse_kernel<<<(N + 255) / 256, 256, 0, stream>>>(stats, lse, N, 108);

  // ---- pass C: recompute logits, write logit - lse ----
  gemm_final_kernel<1><<<dim3(54, 54), 256, 0, stream>>>(h4b, W2t, b2, lse, (float*)d_out, N, N);

  (void)in_sizes; (void)n_in; (void)out_size; (void)ws_size;
}